// Round 7
// baseline (244.246 us; speedup 1.0000x reference)
//
#include <hip/hip_runtime.h>
#include <cstdint>

#define FARV 1e10f

constexpr int NC  = 256;   // coarse samples per ray
constexpr int NS  = 128;   // importance samples per ray
constexpr int NF  = 384;   // fine samples per ray
constexpr int RPB = 4;     // rays (waves) per block
constexpr int ZFP = 400;   // padded zf row: phys = i + (i>>5), max 394

// ---------------- DPP helpers (gfx9 encodings, valid on gfx950) ----------------
// row_shr:N = 0x110|N, wave_shl1 = 0x130, wave_shr1 = 0x138,
// bcast15 = 0x142, bcast31 = 0x143, quad_perm = 0x00..0xFF
template<int CTRL, int RM, int BM>
__device__ __forceinline__ float dppf(float old, float x) {
  return __int_as_float(__builtin_amdgcn_update_dpp(
      __float_as_int(old), __float_as_int(x), CTRL, RM, BM, false));
}
template<int CTRL, int RM, int BM>
__device__ __forceinline__ int dppi(int old, int x) {
  return __builtin_amdgcn_update_dpp(old, x, CTRL, RM, BM, false);
}
template<int CTRL>
__device__ __forceinline__ float dppq(float x) {  // full permutation (quad_perm)
  return __int_as_float(__builtin_amdgcn_update_dpp(
      0, __float_as_int(x), CTRL, 0xf, 0xf, true));
}
template<int MASK>
__device__ __forceinline__ float swzx(float x) {  // xor swizzle within 32-lane halves
  return __int_as_float(__builtin_amdgcn_ds_swizzle(
      __float_as_int(x), (MASK << 10) | 0x1f));
}

__device__ __forceinline__ float scan_incl_mul(float x) {
  x *= dppf<0x111, 0xf, 0xf>(1.f, x);
  x *= dppf<0x112, 0xf, 0xf>(1.f, x);
  x *= dppf<0x114, 0xf, 0xf>(1.f, x);
  x *= dppf<0x118, 0xf, 0xf>(1.f, x);
  x *= dppf<0x142, 0xa, 0xf>(1.f, x);
  x *= dppf<0x143, 0xc, 0xf>(1.f, x);
  return x;
}
__device__ __forceinline__ float scan_incl_add(float x) {
  x += dppf<0x111, 0xf, 0xf>(0.f, x);
  x += dppf<0x112, 0xf, 0xf>(0.f, x);
  x += dppf<0x114, 0xf, 0xf>(0.f, x);
  x += dppf<0x118, 0xf, 0xf>(0.f, x);
  x += dppf<0x142, 0xa, 0xf>(0.f, x);
  x += dppf<0x143, 0xc, 0xf>(0.f, x);
  return x;
}
__device__ __forceinline__ int scan_incl_addi(int x) {
  x += dppi<0x111, 0xf, 0xf>(0, x);
  x += dppi<0x112, 0xf, 0xf>(0, x);
  x += dppi<0x114, 0xf, 0xf>(0, x);
  x += dppi<0x118, 0xf, 0xf>(0, x);
  x += dppi<0x142, 0xa, 0xf>(0, x);
  x += dppi<0x143, 0xc, 0xf>(0, x);
  return x;
}
__device__ __forceinline__ float wshr1(float x, float id) { return dppf<0x138, 0xf, 0xf>(id, x); }
__device__ __forceinline__ int   wshr1i(int x)            { return dppi<0x138, 0xf, 0xf>(0, x); }
__device__ __forceinline__ float wshl1(float x)           { return dppf<0x130, 0xf, 0xf>(0.f, x); }

__device__ __forceinline__ void cmpswap_local(float& a, float& b, bool asc) {
  const float lo = fminf(a, b), hi = fmaxf(a, b);
  a = asc ? lo : hi;
  b = asc ? hi : lo;
}

template<int M>
__device__ __forceinline__ float xpartner(float v) {
  if constexpr (M == 1)       return dppq<0xB1>(v);      // quad_perm [1,0,3,2]
  else if constexpr (M == 2)  return dppq<0x4E>(v);      // quad_perm [2,3,0,1]
  else if constexpr (M <= 16) return swzx<M>(v);
  else                        return __shfl_xor(v, M);
}
template<int M>
__device__ __forceinline__ void merge_down(float& v0, float& v1, bool asc, int lane) {
  const bool tm = ((lane & M) == 0) == asc;
  const float p0 = xpartner<M>(v0);
  const float p1 = xpartner<M>(v1);
  v0 = tm ? fminf(v0, p0) : fmaxf(v0, p0);
  v1 = tm ? fminf(v1, p1) : fmaxf(v1, p1);
  if constexpr (M > 1) merge_down<M / 2>(v0, v1, asc, lane);
}
template<int K>
__device__ __forceinline__ void bitonic_stage(float& v0, float& v1, int lane) {
  const bool asc = (lane & (K >> 1)) == 0;
  merge_down<K / 4>(v0, v1, asc, lane);
  cmpswap_local(v0, v1, asc);
}
// sort 128 floats, 2/lane, elem e = 2*lane+slot, ascending
__device__ __forceinline__ void bitonic_sort128(float& v0, float& v1, int lane) {
  cmpswap_local(v0, v1, (lane & 1) == 0);
  bitonic_stage<4>(v0, v1, lane);
  bitonic_stage<8>(v0, v1, lane);
  bitonic_stage<16>(v0, v1, lane);
  bitonic_stage<32>(v0, v1, lane);
  bitonic_stage<64>(v0, v1, lane);
  bitonic_stage<128>(v0, v1, lane);
}

__global__ __launch_bounds__(256, 8) void vr_kernel(
    const float* __restrict__ z_vals,
    const float* __restrict__ density,
    const float* __restrict__ feature,
    const float* __restrict__ fine_density,
    const float* __restrict__ fine_feature,
    const float* __restrict__ u_rand,
    float* __restrict__ out)
{
  // All rows are WAVE-PRIVATE ([wid]) -> no __syncthreads anywhere; per-wave
  // in-order DS execution + compiler lgkmcnt tracking give the ordering.
  __shared__ __align__(16) float zv[RPB][NC];     // coarse z (sorted)
  __shared__ __align__(16) float cdfs[RPB][NC];   // cdf[0..255], float4-written
  __shared__ __align__(16) float cdfg[RPB][64];   // group heads cdf[4g]
  __shared__ __align__(16) int   Hh[RPB][NC];     // histogram of insertion idx
  __shared__ __align__(16) float zf[RPB][ZFP];    // merged z (padded); later wf (unpadded)

  const int wid  = threadIdx.x >> 6;
  const int lane = threadIdx.x & 63;
  const int ray  = blockIdx.x * RPB + wid;

  float* const zfr = &zf[wid][0];

  // ============ issue ALL global loads up front (MLP: latency hides under
  // the coarse/sort/merge phases; addresses are pure (ray,lane) functions) ====
  const float2 uu = *(const float2*)(u_rand + (size_t)ray * NS + lane * 2);
  const float4 z4 = *(const float4*)(z_vals  + (size_t)ray * NC + lane * 4);
  const float4 d4 = *(const float4*)(density + (size_t)ray * NC + lane * 4);
  const float4 fA = *(const float4*)(feature + (size_t)ray * NC * 3 + lane * 12);
  const float4 fB = *(const float4*)(feature + (size_t)ray * NC * 3 + lane * 12 + 4);
  const float4 fC = *(const float4*)(feature + (size_t)ray * NC * 3 + lane * 12 + 8);
  // fine inputs (used only in the last third of the kernel)
  const float* fd = fine_density + (size_t)ray * NF + 6 * lane;
  const float2 q0 = *(const float2*)(fd);
  const float2 q1 = *(const float2*)(fd + 2);
  const float2 q2 = *(const float2*)(fd + 4);
  const float* fb = fine_feature + (size_t)ray * (NF * 3) + lane * 12;
  const float4 ga = *(const float4*)(fb);
  const float4 gb = *(const float4*)(fb + 4);
  const float4 gc = *(const float4*)(fb + 8);
  const float* fb2 = fine_feature + (size_t)ray * (NF * 3) + 768 + lane * 6;
  const float2 qa = *(const float2*)(fb2);
  const float2 qb = *(const float2*)(fb2 + 2);
  const float2 qc = *(const float2*)(fb2 + 4);

  // zero histogram
  *(int4*)(&Hh[wid][lane * 4]) = make_int4(0, 0, 0, 0);

  // ---------------- coarse pass (4 samples / lane) ----------------
  *(float4*)(&zv[wid][lane * 4]) = z4;

  const float znext = wshl1(z4.x);           // lane l gets lane l+1's z4.x
  const float dl0 = z4.y - z4.x;
  const float dl1 = z4.z - z4.y;
  const float dl2 = z4.w - z4.z;
  const float dl3 = (lane == 63) ? FARV : (znext - z4.w);

  const float e0 = __expf(-d4.x * dl0);
  const float e1 = __expf(-d4.y * dl1);
  const float e2 = __expf(-d4.z * dl2);
  const float e3 = __expf(-d4.w * dl3);

  const float p1 = e0, p2 = e0 * e1, p3 = p2 * e2, ptot = p3 * e3;
  const float incl = scan_incl_mul(ptot);
  const float Tb = wshr1(incl, 1.0f);        // exclusive product, lane0 = 1

  const float w0 = Tb *      (1.0f - e0) + 1e-10f;
  const float w1 = Tb * p1 * (1.0f - e1) + 1e-10f;
  const float w2 = Tb * p2 * (1.0f - e2) + 1e-10f;
  const float w3 = Tb * p3 * (1.0f - e3) + 1e-10f;

  // feature layout per lane: fA={f0.xyz,f1.x} fB={f1.yz,f2.xy} fC={f2.z,f3.xyz}
  float fx = w0 * fA.x + w1 * fA.w + w2 * fB.z + w3 * fC.y;
  float fy = w0 * fA.y + w1 * fB.x + w2 * fB.w + w3 * fC.z;
  float fz = w0 * fA.z + w1 * fB.y + w2 * fC.x + w3 * fC.w;
  float dep = w0 * z4.x + w1 * z4.y + w2 * z4.z + w3 * z4.w;

  // ---------------- CDF over w[1:255] ----------------
  const float wn0 = wshl1(w0);               // next lane's w0 (lane63 guarded)
  const bool l63 = (lane == 63);
  const float m0 = w1 + 1e-5f;
  const float m1 = w2 + 1e-5f;
  const float m2 = l63 ? 0.0f : (w3 + 1e-5f);
  const float m3 = l63 ? 0.0f : (wn0 + 1e-5f);
  const float c1 = m0 + m1;
  const float c2 = c1 + m2;
  const float c3 = c2 + m3;
  const float inclS = scan_incl_add(c3);
  const float Sb = wshr1(inclS, 0.0f);       // exclusive sum = cdf[4*lane] (unnorm)
  const float total = __int_as_float(__builtin_amdgcn_readlane(__float_as_int(inclS), 63));
  const float inv = 1.0f / total;

  *(float4*)(&cdfs[wid][4 * lane]) =
      make_float4(Sb * inv, (Sb + m0) * inv, (Sb + c1) * inv, (Sb + c2) * inv);
  cdfg[wid][lane] = Sb * inv;                // group head cdf[4*lane]

  // ---------------- sort the u's (rank of s == rank of u; s monotone in u) ----
  float v0 = uu.x, v1 = uu.y;
  bitonic_sort128(v0, v1, lane);             // sorted elems 2*lane, 2*lane+1

  // ---------------- importance sampling on sorted u's (2 / lane) ----------------
#pragma unroll
  for (int t = 0; t < 2; ++t) {
    const float u = t ? v1 : v0;
    // 6-level search over 64 group heads: last g with cdf[4g] <= u
    int g = 0;
#pragma unroll
    for (int st = 32; st; st >>= 1) {
      const int cand = g + st;               // <= 63
      if (cdfg[wid][cand] <= u) g = cand;
    }
    const float4 f4 = *(const float4*)(&cdfs[wid][4 * g]);
    const float nxt = cdfs[wid][(4 * g + 4 < 256) ? 4 * g + 4 : 255];
    const int ind = 4 * g + 1 + ((u >= f4.y) ? 1 : 0) + ((u >= f4.z) ? 1 : 0)
                              + ((u >= f4.w) ? 1 : 0);           // upper_bound
    const int below = ind - 1;
    const int r = ind - 4 * g;                                   // 1..4
    const float cb = (r == 1) ? f4.x : (r == 2) ? f4.y : (r == 3) ? f4.z : f4.w;
    float ca = (r == 1) ? f4.y : (r == 2) ? f4.z : (r == 3) ? f4.w : nxt;
    if (ind > 254) ca = f4.z;                // clamp above to 254 (unreachable guard)
    const float zb0 = zv[wid][below];
    const float zb1 = zv[wid][below + 1];
    const float zb2 = zv[wid][(below + 2 < 256) ? below + 2 : 255];
    const float bb = 0.5f * (zb0 + zb1);
    const float ba = 0.5f * (zb1 + zb2);
    float den = ca - cb;
    den = (den < 1e-5f) ? 1.0f : den;
    const float tt = (u - cb) / den;
    const float s = bb + tt * (ba - bb);
    // insertion position among coarse z: s in [zv[below], zv[below+2]]
    int u_ = below + 1 + ((s >= zb1) ? 1 : 0) + ((s >= zb2) ? 1 : 0);
    const int up = (u_ > 255) ? 255 : u_;
    atomicAdd(&Hh[wid][up], 1);
    // among-samples rank == sorted index; scatter into padded zf
    const int si = up + 2 * lane + t;
    zfr[si + (si >> 5)] = s;
  }

  // z ranks: i + inclusive-prefix of histogram at i
  const int4 h4 = *(const int4*)(&Hh[wid][4 * lane]);
  const int t0 = h4.x;
  const int t1 = t0 + h4.y;
  const int t2 = t1 + h4.z;
  const int t3 = t2 + h4.w;
  const int inclH = scan_incl_addi(t3);
  const int Hb = wshr1i(inclH);              // exclusive, lane0 = 0

  {
    const int i0 = 4 * lane + 0 + Hb + t0;
    const int i1 = 4 * lane + 1 + Hb + t1;
    const int i2 = 4 * lane + 2 + Hb + t2;
    const int i3 = 4 * lane + 3 + Hb + t3;
    zfr[i0 + (i0 >> 5)] = z4.x;
    zfr[i1 + (i1 >> 5)] = z4.y;
    zfr[i2 + (i2 >> 5)] = z4.z;
    zfr[i3 + (i3 >> 5)] = z4.w;
  }

  // ---------------- fine pass (6 samples / lane, padded reads) ----------------
  const int p0 = 6 * lane;
  float zq[7];
  {
    const float2 a = *(const float2*)(zfr + p0     + (p0 >> 5));
    const float2 b = *(const float2*)(zfr + p0 + 2 + ((p0 + 2) >> 5));
    const float2 c = *(const float2*)(zfr + p0 + 4 + ((p0 + 4) >> 5));
    zq[0] = a.x; zq[1] = a.y; zq[2] = b.x; zq[3] = b.y; zq[4] = c.x; zq[5] = c.y;
    zq[6] = (lane < 63) ? zfr[p0 + 6 + ((p0 + 6) >> 5)] : 0.0f;
  }

  float dlf[6];
#pragma unroll
  for (int j = 0; j < 5; ++j) dlf[j] = zq[j + 1] - zq[j];
  dlf[5] = (lane == 63) ? FARV : (zq[6] - zq[5]);

  const float fdv[6] = {q0.x, q0.y, q1.x, q1.y, q2.x, q2.y};

  float ee[6];
#pragma unroll
  for (int j = 0; j < 6; ++j) ee[j] = __expf(-fdv[j] * dlf[j]);

  float P[6];
  P[0] = 1.0f;
#pragma unroll
  for (int j = 1; j < 6; ++j) P[j] = P[j - 1] * ee[j - 1];
  const float ftot = P[5] * ee[5];

  const float incF = scan_incl_mul(ftot);
  const float Tb2 = wshr1(incF, 1.0f);

  float wfv[6];
  float fdep = 0.0f;
#pragma unroll
  for (int j = 0; j < 6; ++j) {
    wfv[j] = Tb2 * P[j] * (1.0f - ee[j]) + 1e-10f;
    fdep += wfv[j] * zq[j];
  }

  // keep the padded zf reads above ordered before the unpadded wf writes below
  __builtin_amdgcn_sched_barrier(0);

  // store wf UNPADDED into zf (zf fully consumed; wave-private)
  zfr[p0 + 0] = wfv[0];
  zfr[p0 + 1] = wfv[1];
  zfr[p0 + 2] = wfv[2];
  zfr[p0 + 3] = wfv[3];
  zfr[p0 + 4] = wfv[4];
  zfr[p0 + 5] = wfv[5];

  // ---------------- feature accumulation over ALL 384 samples ----------------
  // samples 0..255: 4/lane (weights from LDS, features already in registers)
  const float4 wq = *(const float4*)(zfr + 4 * lane);   // aligned, conflict-free
  // sample 4l+0: ga.xyz; 4l+1: ga.w,gb.x,gb.y; 4l+2: gb.z,gb.w,gc.x; 4l+3: gc.y,gc.z,gc.w
  float gx = wq.x * ga.x + wq.y * ga.w + wq.z * gb.z + wq.w * gc.y;
  float gy = wq.x * ga.y + wq.y * gb.x + wq.z * gb.w + wq.w * gc.z;
  float gz = wq.x * ga.z + wq.y * gb.y + wq.z * gc.x + wq.w * gc.w;

  // samples 256..383: 2/lane
  const float2 wt2 = *(const float2*)(zfr + 256 + 2 * lane);
  // sample 256+2l: qa.x,qa.y,qb.x ; sample 257+2l: qb.y,qc.x,qc.y
  gx += wt2.x * qa.x + wt2.y * qb.y;
  gy += wt2.x * qa.y + wt2.y * qc.x;
  gz += wt2.x * qb.x + wt2.y * qc.y;

  // ---------------- reductions (DPP, result in lane 63) + output ----------------
  fx   = scan_incl_add(fx);
  fy   = scan_incl_add(fy);
  fz   = scan_incl_add(fz);
  dep  = scan_incl_add(dep);
  gx   = scan_incl_add(gx);
  gy   = scan_incl_add(gy);
  gz   = scan_incl_add(gz);
  fdep = scan_incl_add(fdep);

  if (lane == 63) {
    float* o = out + (size_t)ray * 8;
    *(float4*)(o)     = make_float4(fx, fy, fz, dep);
    *(float4*)(o + 4) = make_float4(gx, gy, gz, fdep);
  }
}

extern "C" void kernel_launch(void* const* d_in, const int* in_sizes, int n_in,
                              void* d_out, int out_size, void* d_ws, size_t ws_size,
                              hipStream_t stream) {
  const float* z_vals       = (const float*)d_in[0];
  const float* density      = (const float*)d_in[1];
  const float* feature      = (const float*)d_in[2];
  const float* fine_density = (const float*)d_in[3];
  const float* fine_feature = (const float*)d_in[4];
  const float* u_rand       = (const float*)d_in[5];
  float* out = (float*)d_out;

  const int B = in_sizes[0] / NC;       // 65536
  dim3 grid(B / RPB), block(RPB * 64);
  hipLaunchKernelGGL(vr_kernel, grid, block, 0, stream,
                     z_vals, density, feature, fine_density, fine_feature,
                     u_rand, out);
}

// Round 8
// 130.133 us; speedup vs baseline: 1.8769x; 1.8769x over previous
//
#include <hip/hip_runtime.h>
#include <cstdint>

#define FARV 1e10f

constexpr int NC  = 256;   // coarse samples per ray
constexpr int NS  = 128;   // importance samples per ray
constexpr int NF  = 384;   // fine samples per ray
constexpr int RPB = 4;     // rays (waves) per block
constexpr int ZFP = 400;   // padded zf row: phys = i + (i>>5), max 394

// ---------------- DPP helpers (gfx9 encodings, valid on gfx950) ----------------
// row_shr:N = 0x110|N, wave_shl1 = 0x130, wave_shr1 = 0x138,
// bcast15 = 0x142, bcast31 = 0x143, quad_perm = 0x00..0xFF
template<int CTRL, int RM, int BM>
__device__ __forceinline__ float dppf(float old, float x) {
  return __int_as_float(__builtin_amdgcn_update_dpp(
      __float_as_int(old), __float_as_int(x), CTRL, RM, BM, false));
}
template<int CTRL, int RM, int BM>
__device__ __forceinline__ int dppi(int old, int x) {
  return __builtin_amdgcn_update_dpp(old, x, CTRL, RM, BM, false);
}
template<int CTRL>
__device__ __forceinline__ float dppq(float x) {  // full permutation (quad_perm)
  return __int_as_float(__builtin_amdgcn_update_dpp(
      0, __float_as_int(x), CTRL, 0xf, 0xf, true));
}
template<int MASK>
__device__ __forceinline__ float swzx(float x) {  // xor swizzle within 32-lane halves
  return __int_as_float(__builtin_amdgcn_ds_swizzle(
      __float_as_int(x), (MASK << 10) | 0x1f));
}

__device__ __forceinline__ float scan_incl_mul(float x) {
  x *= dppf<0x111, 0xf, 0xf>(1.f, x);
  x *= dppf<0x112, 0xf, 0xf>(1.f, x);
  x *= dppf<0x114, 0xf, 0xf>(1.f, x);
  x *= dppf<0x118, 0xf, 0xf>(1.f, x);
  x *= dppf<0x142, 0xa, 0xf>(1.f, x);
  x *= dppf<0x143, 0xc, 0xf>(1.f, x);
  return x;
}
__device__ __forceinline__ float scan_incl_add(float x) {
  x += dppf<0x111, 0xf, 0xf>(0.f, x);
  x += dppf<0x112, 0xf, 0xf>(0.f, x);
  x += dppf<0x114, 0xf, 0xf>(0.f, x);
  x += dppf<0x118, 0xf, 0xf>(0.f, x);
  x += dppf<0x142, 0xa, 0xf>(0.f, x);
  x += dppf<0x143, 0xc, 0xf>(0.f, x);
  return x;
}
__device__ __forceinline__ int scan_incl_addi(int x) {
  x += dppi<0x111, 0xf, 0xf>(0, x);
  x += dppi<0x112, 0xf, 0xf>(0, x);
  x += dppi<0x114, 0xf, 0xf>(0, x);
  x += dppi<0x118, 0xf, 0xf>(0, x);
  x += dppi<0x142, 0xa, 0xf>(0, x);
  x += dppi<0x143, 0xc, 0xf>(0, x);
  return x;
}
__device__ __forceinline__ float wshr1(float x, float id) { return dppf<0x138, 0xf, 0xf>(id, x); }
__device__ __forceinline__ int   wshr1i(int x)            { return dppi<0x138, 0xf, 0xf>(0, x); }
__device__ __forceinline__ float wshl1(float x)           { return dppf<0x130, 0xf, 0xf>(0.f, x); }

__device__ __forceinline__ void cmpswap_local(float& a, float& b, bool asc) {
  const float lo = fminf(a, b), hi = fmaxf(a, b);
  a = asc ? lo : hi;
  b = asc ? hi : lo;
}

template<int M>
__device__ __forceinline__ float xpartner(float v) {
  if constexpr (M == 1)       return dppq<0xB1>(v);      // quad_perm [1,0,3,2]
  else if constexpr (M == 2)  return dppq<0x4E>(v);      // quad_perm [2,3,0,1]
  else if constexpr (M <= 16) return swzx<M>(v);
  else                        return __shfl_xor(v, M);
}
template<int M>
__device__ __forceinline__ void merge_down(float& v0, float& v1, bool asc, int lane) {
  const bool tm = ((lane & M) == 0) == asc;
  const float p0 = xpartner<M>(v0);
  const float p1 = xpartner<M>(v1);
  v0 = tm ? fminf(v0, p0) : fmaxf(v0, p0);
  v1 = tm ? fminf(v1, p1) : fmaxf(v1, p1);
  if constexpr (M > 1) merge_down<M / 2>(v0, v1, asc, lane);
}
template<int K>
__device__ __forceinline__ void bitonic_stage(float& v0, float& v1, int lane) {
  const bool asc = (lane & (K >> 1)) == 0;
  merge_down<K / 4>(v0, v1, asc, lane);
  cmpswap_local(v0, v1, asc);
}
// sort 128 floats, 2/lane, elem e = 2*lane+slot, ascending
__device__ __forceinline__ void bitonic_sort128(float& v0, float& v1, int lane) {
  cmpswap_local(v0, v1, (lane & 1) == 0);
  bitonic_stage<4>(v0, v1, lane);
  bitonic_stage<8>(v0, v1, lane);
  bitonic_stage<16>(v0, v1, lane);
  bitonic_stage<32>(v0, v1, lane);
  bitonic_stage<64>(v0, v1, lane);
  bitonic_stage<128>(v0, v1, lane);
}

// launch_bounds(256, 6): 6 waves/EU -> VGPR cap ~84. Round-7's (256,8) cap=64
// forced the hoisted fine data to SPILL (WRITE_SIZE 2MB->428MB). 6 blocks/CU
// still gives 24 waves/CU; LDS 6*19968B < 160KB.
__global__ __launch_bounds__(256, 6) void vr_kernel(
    const float* __restrict__ z_vals,
    const float* __restrict__ density,
    const float* __restrict__ feature,
    const float* __restrict__ fine_density,
    const float* __restrict__ fine_feature,
    const float* __restrict__ u_rand,
    float* __restrict__ out)
{
  // All rows are WAVE-PRIVATE ([wid]) -> no __syncthreads anywhere; per-wave
  // in-order DS execution + compiler lgkmcnt tracking give the ordering.
  __shared__ __align__(16) float zv[RPB][NC];     // coarse z (sorted)
  __shared__ __align__(16) float cdfs[RPB][NC];   // cdf[0..255], float4-written
  __shared__ __align__(16) float cdfg[RPB][64];   // group heads cdf[4g]
  __shared__ __align__(16) int   Hh[RPB][NC];     // histogram of insertion idx
  __shared__ __align__(16) float zf[RPB][ZFP];    // merged z (padded); later wf (unpadded)

  const int wid  = threadIdx.x >> 6;
  const int lane = threadIdx.x & 63;
  const int ray  = blockIdx.x * RPB + wid;

  float* const zfr = &zf[wid][0];

  // ============ issue ALL global loads up front (MLP: latency hides under
  // the coarse/sort/merge phases; addresses are pure (ray,lane) functions) ====
  const float2 uu = *(const float2*)(u_rand + (size_t)ray * NS + lane * 2);
  const float4 z4 = *(const float4*)(z_vals  + (size_t)ray * NC + lane * 4);
  const float4 d4 = *(const float4*)(density + (size_t)ray * NC + lane * 4);
  const float4 fA = *(const float4*)(feature + (size_t)ray * NC * 3 + lane * 12);
  const float4 fB = *(const float4*)(feature + (size_t)ray * NC * 3 + lane * 12 + 4);
  const float4 fC = *(const float4*)(feature + (size_t)ray * NC * 3 + lane * 12 + 8);
  // fine inputs (used only in the last third of the kernel)
  const float* fd = fine_density + (size_t)ray * NF + 6 * lane;
  const float2 q0 = *(const float2*)(fd);
  const float2 q1 = *(const float2*)(fd + 2);
  const float2 q2 = *(const float2*)(fd + 4);
  const float* fb = fine_feature + (size_t)ray * (NF * 3) + lane * 12;
  const float4 ga = *(const float4*)(fb);
  const float4 gb = *(const float4*)(fb + 4);
  const float4 gc = *(const float4*)(fb + 8);
  const float* fb2 = fine_feature + (size_t)ray * (NF * 3) + 768 + lane * 6;
  const float2 qa = *(const float2*)(fb2);
  const float2 qb = *(const float2*)(fb2 + 2);
  const float2 qc = *(const float2*)(fb2 + 4);

  // zero histogram
  *(int4*)(&Hh[wid][lane * 4]) = make_int4(0, 0, 0, 0);

  // ---------------- coarse pass (4 samples / lane) ----------------
  *(float4*)(&zv[wid][lane * 4]) = z4;

  const float znext = wshl1(z4.x);           // lane l gets lane l+1's z4.x
  const float dl0 = z4.y - z4.x;
  const float dl1 = z4.z - z4.y;
  const float dl2 = z4.w - z4.z;
  const float dl3 = (lane == 63) ? FARV : (znext - z4.w);

  const float e0 = __expf(-d4.x * dl0);
  const float e1 = __expf(-d4.y * dl1);
  const float e2 = __expf(-d4.z * dl2);
  const float e3 = __expf(-d4.w * dl3);

  const float p1 = e0, p2 = e0 * e1, p3 = p2 * e2, ptot = p3 * e3;
  const float incl = scan_incl_mul(ptot);
  const float Tb = wshr1(incl, 1.0f);        // exclusive product, lane0 = 1

  const float w0 = Tb *      (1.0f - e0) + 1e-10f;
  const float w1 = Tb * p1 * (1.0f - e1) + 1e-10f;
  const float w2 = Tb * p2 * (1.0f - e2) + 1e-10f;
  const float w3 = Tb * p3 * (1.0f - e3) + 1e-10f;

  // feature layout per lane: fA={f0.xyz,f1.x} fB={f1.yz,f2.xy} fC={f2.z,f3.xyz}
  float fx = w0 * fA.x + w1 * fA.w + w2 * fB.z + w3 * fC.y;
  float fy = w0 * fA.y + w1 * fB.x + w2 * fB.w + w3 * fC.z;
  float fz = w0 * fA.z + w1 * fB.y + w2 * fC.x + w3 * fC.w;
  float dep = w0 * z4.x + w1 * z4.y + w2 * z4.z + w3 * z4.w;

  // ---------------- CDF over w[1:255] ----------------
  const float wn0 = wshl1(w0);               // next lane's w0 (lane63 guarded)
  const bool l63 = (lane == 63);
  const float m0 = w1 + 1e-5f;
  const float m1 = w2 + 1e-5f;
  const float m2 = l63 ? 0.0f : (w3 + 1e-5f);
  const float m3 = l63 ? 0.0f : (wn0 + 1e-5f);
  const float c1 = m0 + m1;
  const float c2 = c1 + m2;
  const float c3 = c2 + m3;
  const float inclS = scan_incl_add(c3);
  const float Sb = wshr1(inclS, 0.0f);       // exclusive sum = cdf[4*lane] (unnorm)
  const float total = __int_as_float(__builtin_amdgcn_readlane(__float_as_int(inclS), 63));
  const float inv = 1.0f / total;

  *(float4*)(&cdfs[wid][4 * lane]) =
      make_float4(Sb * inv, (Sb + m0) * inv, (Sb + c1) * inv, (Sb + c2) * inv);
  cdfg[wid][lane] = Sb * inv;                // group head cdf[4*lane]

  // ---------------- sort the u's (rank of s == rank of u; s monotone in u) ----
  float v0 = uu.x, v1 = uu.y;
  bitonic_sort128(v0, v1, lane);             // sorted elems 2*lane, 2*lane+1

  // ---------------- importance sampling on sorted u's (2 / lane) ----------------
#pragma unroll
  for (int t = 0; t < 2; ++t) {
    const float u = t ? v1 : v0;
    // 6-level search over 64 group heads: last g with cdf[4g] <= u
    int g = 0;
#pragma unroll
    for (int st = 32; st; st >>= 1) {
      const int cand = g + st;               // <= 63
      if (cdfg[wid][cand] <= u) g = cand;
    }
    const float4 f4 = *(const float4*)(&cdfs[wid][4 * g]);
    const float nxt = cdfs[wid][(4 * g + 4 < 256) ? 4 * g + 4 : 255];
    const int ind = 4 * g + 1 + ((u >= f4.y) ? 1 : 0) + ((u >= f4.z) ? 1 : 0)
                              + ((u >= f4.w) ? 1 : 0);           // upper_bound
    const int below = ind - 1;
    const int r = ind - 4 * g;                                   // 1..4
    const float cb = (r == 1) ? f4.x : (r == 2) ? f4.y : (r == 3) ? f4.z : f4.w;
    float ca = (r == 1) ? f4.y : (r == 2) ? f4.z : (r == 3) ? f4.w : nxt;
    if (ind > 254) ca = f4.z;                // clamp above to 254 (unreachable guard)
    const float zb0 = zv[wid][below];
    const float zb1 = zv[wid][below + 1];
    const float zb2 = zv[wid][(below + 2 < 256) ? below + 2 : 255];
    const float bb = 0.5f * (zb0 + zb1);
    const float ba = 0.5f * (zb1 + zb2);
    float den = ca - cb;
    den = (den < 1e-5f) ? 1.0f : den;
    const float tt = (u - cb) / den;
    const float s = bb + tt * (ba - bb);
    // insertion position among coarse z: s in [zv[below], zv[below+2]]
    int u_ = below + 1 + ((s >= zb1) ? 1 : 0) + ((s >= zb2) ? 1 : 0);
    const int up = (u_ > 255) ? 255 : u_;
    atomicAdd(&Hh[wid][up], 1);
    // among-samples rank == sorted index; scatter into padded zf
    const int si = up + 2 * lane + t;
    zfr[si + (si >> 5)] = s;
  }

  // z ranks: i + inclusive-prefix of histogram at i
  const int4 h4 = *(const int4*)(&Hh[wid][4 * lane]);
  const int t0 = h4.x;
  const int t1 = t0 + h4.y;
  const int t2 = t1 + h4.z;
  const int t3 = t2 + h4.w;
  const int inclH = scan_incl_addi(t3);
  const int Hb = wshr1i(inclH);              // exclusive, lane0 = 0

  {
    const int i0 = 4 * lane + 0 + Hb + t0;
    const int i1 = 4 * lane + 1 + Hb + t1;
    const int i2 = 4 * lane + 2 + Hb + t2;
    const int i3 = 4 * lane + 3 + Hb + t3;
    zfr[i0 + (i0 >> 5)] = z4.x;
    zfr[i1 + (i1 >> 5)] = z4.y;
    zfr[i2 + (i2 >> 5)] = z4.z;
    zfr[i3 + (i3 >> 5)] = z4.w;
  }

  // ---------------- fine pass (6 samples / lane, padded reads) ----------------
  const int p0 = 6 * lane;
  float zq[7];
  {
    const float2 a = *(const float2*)(zfr + p0     + (p0 >> 5));
    const float2 b = *(const float2*)(zfr + p0 + 2 + ((p0 + 2) >> 5));
    const float2 c = *(const float2*)(zfr + p0 + 4 + ((p0 + 4) >> 5));
    zq[0] = a.x; zq[1] = a.y; zq[2] = b.x; zq[3] = b.y; zq[4] = c.x; zq[5] = c.y;
    zq[6] = (lane < 63) ? zfr[p0 + 6 + ((p0 + 6) >> 5)] : 0.0f;
  }

  float dlf[6];
#pragma unroll
  for (int j = 0; j < 5; ++j) dlf[j] = zq[j + 1] - zq[j];
  dlf[5] = (lane == 63) ? FARV : (zq[6] - zq[5]);

  const float fdv[6] = {q0.x, q0.y, q1.x, q1.y, q2.x, q2.y};

  float ee[6];
#pragma unroll
  for (int j = 0; j < 6; ++j) ee[j] = __expf(-fdv[j] * dlf[j]);

  float P[6];
  P[0] = 1.0f;
#pragma unroll
  for (int j = 1; j < 6; ++j) P[j] = P[j - 1] * ee[j - 1];
  const float ftot = P[5] * ee[5];

  const float incF = scan_incl_mul(ftot);
  const float Tb2 = wshr1(incF, 1.0f);

  float wfv[6];
  float fdep = 0.0f;
#pragma unroll
  for (int j = 0; j < 6; ++j) {
    wfv[j] = Tb2 * P[j] * (1.0f - ee[j]) + 1e-10f;
    fdep += wfv[j] * zq[j];
  }

  // keep the padded zf reads above ordered before the unpadded wf writes below
  __builtin_amdgcn_sched_barrier(0);

  // store wf UNPADDED into zf (zf fully consumed; wave-private)
  zfr[p0 + 0] = wfv[0];
  zfr[p0 + 1] = wfv[1];
  zfr[p0 + 2] = wfv[2];
  zfr[p0 + 3] = wfv[3];
  zfr[p0 + 4] = wfv[4];
  zfr[p0 + 5] = wfv[5];

  // ---------------- feature accumulation over ALL 384 samples ----------------
  // samples 0..255: 4/lane (weights from LDS, features already in registers)
  const float4 wq = *(const float4*)(zfr + 4 * lane);   // aligned, conflict-free
  // sample 4l+0: ga.xyz; 4l+1: ga.w,gb.x,gb.y; 4l+2: gb.z,gb.w,gc.x; 4l+3: gc.y,gc.z,gc.w
  float gx = wq.x * ga.x + wq.y * ga.w + wq.z * gb.z + wq.w * gc.y;
  float gy = wq.x * ga.y + wq.y * gb.x + wq.z * gb.w + wq.w * gc.z;
  float gz = wq.x * ga.z + wq.y * gb.y + wq.z * gc.x + wq.w * gc.w;

  // samples 256..383: 2/lane
  const float2 wt2 = *(const float2*)(zfr + 256 + 2 * lane);
  // sample 256+2l: qa.x,qa.y,qb.x ; sample 257+2l: qb.y,qc.x,qc.y
  gx += wt2.x * qa.x + wt2.y * qb.y;
  gy += wt2.x * qa.y + wt2.y * qc.x;
  gz += wt2.x * qb.x + wt2.y * qc.y;

  // ---------------- reductions (DPP, result in lane 63) + output ----------------
  fx   = scan_incl_add(fx);
  fy   = scan_incl_add(fy);
  fz   = scan_incl_add(fz);
  dep  = scan_incl_add(dep);
  gx   = scan_incl_add(gx);
  gy   = scan_incl_add(gy);
  gz   = scan_incl_add(gz);
  fdep = scan_incl_add(fdep);

  if (lane == 63) {
    float* o = out + (size_t)ray * 8;
    *(float4*)(o)     = make_float4(fx, fy, fz, dep);
    *(float4*)(o + 4) = make_float4(gx, gy, gz, fdep);
  }
}

extern "C" void kernel_launch(void* const* d_in, const int* in_sizes, int n_in,
                              void* d_out, int out_size, void* d_ws, size_t ws_size,
                              hipStream_t stream) {
  const float* z_vals       = (const float*)d_in[0];
  const float* density      = (const float*)d_in[1];
  const float* feature      = (const float*)d_in[2];
  const float* fine_density = (const float*)d_in[3];
  const float* fine_feature = (const float*)d_in[4];
  const float* u_rand       = (const float*)d_in[5];
  float* out = (float*)d_out;

  const int B = in_sizes[0] / NC;       // 65536
  dim3 grid(B / RPB), block(RPB * 64);
  hipLaunchKernelGGL(vr_kernel, grid, block, 0, stream,
                     z_vals, density, feature, fine_density, fine_feature,
                     u_rand, out);
}

// Round 9
// 128.861 us; speedup vs baseline: 1.8954x; 1.0099x over previous
//
#include <hip/hip_runtime.h>
#include <cstdint>

#define FARV 1e10f

constexpr int NC  = 256;   // coarse samples per ray
constexpr int NS  = 128;   // importance samples per ray
constexpr int NF  = 384;   // fine samples per ray
constexpr int RPB = 4;     // rays (waves) per block
constexpr int ZFP = 400;   // padded zf row: phys = i + (i>>5), max 394

// ---------------- DPP helpers (gfx9 encodings, valid on gfx950) ----------------
template<int CTRL, int RM, int BM>
__device__ __forceinline__ float dppf(float old, float x) {
  return __int_as_float(__builtin_amdgcn_update_dpp(
      __float_as_int(old), __float_as_int(x), CTRL, RM, BM, false));
}
template<int CTRL, int RM, int BM>
__device__ __forceinline__ int dppi(int old, int x) {
  return __builtin_amdgcn_update_dpp(old, x, CTRL, RM, BM, false);
}
template<int CTRL>
__device__ __forceinline__ float dppq(float x) {  // full permutation (quad_perm)
  return __int_as_float(__builtin_amdgcn_update_dpp(
      0, __float_as_int(x), CTRL, 0xf, 0xf, true));
}
template<int MASK>
__device__ __forceinline__ float swzx(float x) {  // xor swizzle within 32-lane halves
  return __int_as_float(__builtin_amdgcn_ds_swizzle(
      __float_as_int(x), (MASK << 10) | 0x1f));
}
__device__ __forceinline__ float rdlane(float x, int l) {
  return __int_as_float(__builtin_amdgcn_readlane(__float_as_int(x), l));
}

__device__ __forceinline__ float scan_incl_mul(float x) {
  x *= dppf<0x111, 0xf, 0xf>(1.f, x);
  x *= dppf<0x112, 0xf, 0xf>(1.f, x);
  x *= dppf<0x114, 0xf, 0xf>(1.f, x);
  x *= dppf<0x118, 0xf, 0xf>(1.f, x);
  x *= dppf<0x142, 0xa, 0xf>(1.f, x);
  x *= dppf<0x143, 0xc, 0xf>(1.f, x);
  return x;
}
__device__ __forceinline__ float scan_incl_add(float x) {
  x += dppf<0x111, 0xf, 0xf>(0.f, x);
  x += dppf<0x112, 0xf, 0xf>(0.f, x);
  x += dppf<0x114, 0xf, 0xf>(0.f, x);
  x += dppf<0x118, 0xf, 0xf>(0.f, x);
  x += dppf<0x142, 0xa, 0xf>(0.f, x);
  x += dppf<0x143, 0xc, 0xf>(0.f, x);
  return x;
}
__device__ __forceinline__ int scan_incl_addi(int x) {
  x += dppi<0x111, 0xf, 0xf>(0, x);
  x += dppi<0x112, 0xf, 0xf>(0, x);
  x += dppi<0x114, 0xf, 0xf>(0, x);
  x += dppi<0x118, 0xf, 0xf>(0, x);
  x += dppi<0x142, 0xa, 0xf>(0, x);
  x += dppi<0x143, 0xc, 0xf>(0, x);
  return x;
}
__device__ __forceinline__ float wshr1(float x, float id) { return dppf<0x138, 0xf, 0xf>(id, x); }
__device__ __forceinline__ int   wshr1i(int x)            { return dppi<0x138, 0xf, 0xf>(0, x); }
__device__ __forceinline__ float wshl1(float x)           { return dppf<0x130, 0xf, 0xf>(0.f, x); }

__device__ __forceinline__ void cmpswap_local(float& a, float& b, bool asc) {
  const float lo = fminf(a, b), hi = fmaxf(a, b);
  a = asc ? lo : hi;
  b = asc ? hi : lo;
}

template<int M>
__device__ __forceinline__ float xpartner(float v) {
  if constexpr (M == 1)       return dppq<0xB1>(v);      // quad_perm [1,0,3,2]
  else if constexpr (M == 2)  return dppq<0x4E>(v);      // quad_perm [2,3,0,1]
  else if constexpr (M <= 16) return swzx<M>(v);
  else                        return __shfl_xor(v, M);
}
template<int M>
__device__ __forceinline__ void merge_down(float& v0, float& v1, bool asc, int lane) {
  const bool tm = ((lane & M) == 0) == asc;
  const float p0 = xpartner<M>(v0);
  const float p1 = xpartner<M>(v1);
  v0 = tm ? fminf(v0, p0) : fmaxf(v0, p0);
  v1 = tm ? fminf(v1, p1) : fmaxf(v1, p1);
  if constexpr (M > 1) merge_down<M / 2>(v0, v1, asc, lane);
}
template<int K>
__device__ __forceinline__ void bitonic_stage(float& v0, float& v1, int lane) {
  const bool asc = (lane & (K >> 1)) == 0;
  merge_down<K / 4>(v0, v1, asc, lane);
  cmpswap_local(v0, v1, asc);
}
// sort 128 floats, 2/lane, elem e = 2*lane+slot, ascending
__device__ __forceinline__ void bitonic_sort128(float& v0, float& v1, int lane) {
  cmpswap_local(v0, v1, (lane & 1) == 0);
  bitonic_stage<4>(v0, v1, lane);
  bitonic_stage<8>(v0, v1, lane);
  bitonic_stage<16>(v0, v1, lane);
  bitonic_stage<32>(v0, v1, lane);
  bitonic_stage<64>(v0, v1, lane);
  bitonic_stage<128>(v0, v1, lane);
}

__global__ __launch_bounds__(256, 8) void vr_kernel(
    const float* __restrict__ z_vals,
    const float* __restrict__ density,
    const float* __restrict__ feature,
    const float* __restrict__ fine_density,
    const float* __restrict__ fine_feature,
    const float* __restrict__ u_rand,
    float* __restrict__ out)
{
  // All rows are WAVE-PRIVATE ([wid]) -> no __syncthreads anywhere.
  __shared__ __align__(16) float zv[RPB][NC];     // coarse z (sorted)
  __shared__ __align__(16) float cdfs[RPB][NC];   // cdf[0..255], float4-written
  __shared__ __align__(16) float cdfg[RPB][64];   // group heads cdf[4g]
  __shared__ __align__(16) int   Hh[RPB][NC];     // histogram of insertion idx
  __shared__ __align__(16) float zf[RPB][ZFP];    // merged z (padded)

  const int wid  = threadIdx.x >> 6;
  const int lane = threadIdx.x & 63;
  const int ray  = blockIdx.x * RPB + wid;

  float* const zfr = &zf[wid][0];

  // zero histogram
  *(int4*)(&Hh[wid][lane * 4]) = make_int4(0, 0, 0, 0);

  // load u early (latency hides under coarse pass)
  const float2 uu = *(const float2*)(u_rand + (size_t)ray * NS + lane * 2);

  // ---------------- coarse pass (4 samples / lane) ----------------
  const float4 z4 = *(const float4*)(z_vals  + (size_t)ray * NC + lane * 4);
  const float4 d4 = *(const float4*)(density + (size_t)ray * NC + lane * 4);
  const float4 fA = *(const float4*)(feature + (size_t)ray * NC * 3 + lane * 12);
  const float4 fB = *(const float4*)(feature + (size_t)ray * NC * 3 + lane * 12 + 4);
  const float4 fC = *(const float4*)(feature + (size_t)ray * NC * 3 + lane * 12 + 8);

  *(float4*)(&zv[wid][lane * 4]) = z4;

  const float znext = wshl1(z4.x);           // lane l gets lane l+1's z4.x
  const float dl0 = z4.y - z4.x;
  const float dl1 = z4.z - z4.y;
  const float dl2 = z4.w - z4.z;
  const float dl3 = (lane == 63) ? FARV : (znext - z4.w);

  const float e0 = __expf(-d4.x * dl0);
  const float e1 = __expf(-d4.y * dl1);
  const float e2 = __expf(-d4.z * dl2);
  const float e3 = __expf(-d4.w * dl3);

  const float p1 = e0, p2 = e0 * e1, p3 = p2 * e2, ptot = p3 * e3;
  const float incl = scan_incl_mul(ptot);
  const float Tb = wshr1(incl, 1.0f);        // exclusive product, lane0 = 1

  const float w0 = Tb *      (1.0f - e0) + 1e-10f;
  const float w1 = Tb * p1 * (1.0f - e1) + 1e-10f;
  const float w2 = Tb * p2 * (1.0f - e2) + 1e-10f;
  const float w3 = Tb * p3 * (1.0f - e3) + 1e-10f;

  // feature layout per lane: fA={f0.xyz,f1.x} fB={f1.yz,f2.xy} fC={f2.z,f3.xyz}
  float fx = w0 * fA.x + w1 * fA.w + w2 * fB.z + w3 * fC.y;
  float fy = w0 * fA.y + w1 * fB.x + w2 * fB.w + w3 * fC.z;
  float fz = w0 * fA.z + w1 * fB.y + w2 * fC.x + w3 * fC.w;
  float dep = w0 * z4.x + w1 * z4.y + w2 * z4.z + w3 * z4.w;

  // ---------------- CDF over w[1:255] ----------------
  const float wn0 = wshl1(w0);               // next lane's w0 (lane63 guarded)
  const bool l63 = (lane == 63);
  const float m0 = w1 + 1e-5f;
  const float m1 = w2 + 1e-5f;
  const float m2 = l63 ? 0.0f : (w3 + 1e-5f);
  const float m3 = l63 ? 0.0f : (wn0 + 1e-5f);
  const float c1 = m0 + m1;
  const float c2 = c1 + m2;
  const float c3 = c2 + m3;
  const float inclS = scan_incl_add(c3);
  const float Sb = wshr1(inclS, 0.0f);       // exclusive sum = cdf[4*lane] (unnorm)
  const float total = rdlane(inclS, 63);
  const float inv = 1.0f / total;
  const float SbI = Sb * inv;                // = cdfg[lane], lives in registers

  *(float4*)(&cdfs[wid][4 * lane]) =
      make_float4(SbI, (Sb + m0) * inv, (Sb + c1) * inv, (Sb + c2) * inv);
  cdfg[wid][lane] = SbI;

  // 8 super-heads (groups 8k) broadcast via readlane -- register-only level A
  const float h1 = rdlane(SbI,  8);
  const float h2 = rdlane(SbI, 16);
  const float h3 = rdlane(SbI, 24);
  const float h4s = rdlane(SbI, 32);
  const float h5 = rdlane(SbI, 40);
  const float h6 = rdlane(SbI, 48);
  const float h7 = rdlane(SbI, 56);

  // ---------------- sort the u's (rank of s == rank of u; s monotone in u) ----
  float v0 = uu.x, v1 = uu.y;
  bitonic_sort128(v0, v1, lane);             // sorted elems 2*lane, 2*lane+1

  // ---------------- importance sampling on sorted u's (2 / lane) ----------------
#pragma unroll
  for (int t = 0; t < 2; ++t) {
    const float u = t ? v1 : v0;
    // level A (registers): block k = last k with head(8k) <= u
    const int k = ((u >= h1) ? 1 : 0) + ((u >= h2) ? 1 : 0) + ((u >= h3) ? 1 : 0)
                + ((u >= h4s) ? 1 : 0) + ((u >= h5) ? 1 : 0) + ((u >= h6) ? 1 : 0)
                + ((u >= h7) ? 1 : 0);
    // level B (one LDS round, two independent float4 reads): g within block
    const float4 cA = *(const float4*)(&cdfg[wid][8 * k]);
    const float4 cB = *(const float4*)(&cdfg[wid][8 * k + 4]);
    const int g = 8 * k
                + ((u >= cA.y) ? 1 : 0) + ((u >= cA.z) ? 1 : 0) + ((u >= cA.w) ? 1 : 0)
                + ((u >= cB.x) ? 1 : 0) + ((u >= cB.y) ? 1 : 0) + ((u >= cB.z) ? 1 : 0)
                + ((u >= cB.w) ? 1 : 0);
    // level C (one LDS round, two independent float4 reads)
    const int g4 = 4 * g;
    const float4 f4 = *(const float4*)(&cdfs[wid][g4]);
    const float4 f4b = *(const float4*)(&cdfs[wid][(g4 + 4 <= 252) ? g4 + 4 : 252]);
    const float nxt = f4b.x;                 // cdfs[4g+4] for g<63; guarded for g=63
    const int ind = g4 + 1 + ((u >= f4.y) ? 1 : 0) + ((u >= f4.z) ? 1 : 0)
                           + ((u >= f4.w) ? 1 : 0);          // upper_bound
    const int below = (ind - 1 < 254) ? ind - 1 : 254;
    const int r = ind - g4;                                  // 1..4
    const float cb = (r == 1) ? f4.x : (r == 2) ? f4.y : (r == 3) ? f4.z : f4.w;
    float ca = (r == 1) ? f4.y : (r == 2) ? f4.z : (r == 3) ? f4.w : nxt;
    if (ind > 254) ca = f4.z;                // matches validated round-6 guard
    const float zb0 = zv[wid][below];
    const float zb1 = zv[wid][below + 1];
    const float zb2 = zv[wid][(below + 2 < 256) ? below + 2 : 255];
    const float bb = 0.5f * (zb0 + zb1);
    const float ba = 0.5f * (zb1 + zb2);
    float den = ca - cb;
    den = (den < 1e-5f) ? 1.0f : den;
    const float tt = (u - cb) / den;
    const float s = bb + tt * (ba - bb);
    // insertion position among coarse z: s in [zv[below], zv[below+2]]
    int u_ = below + 1 + ((s >= zb1) ? 1 : 0) + ((s >= zb2) ? 1 : 0);
    const int up = (u_ > 255) ? 255 : u_;
    atomicAdd(&Hh[wid][up], 1);
    // among-samples rank == sorted index; scatter into padded zf
    const int si = up + 2 * lane + t;
    zfr[si + (si >> 5)] = s;
  }

  // z ranks: i + inclusive-prefix of histogram at i
  const int4 h4 = *(const int4*)(&Hh[wid][4 * lane]);
  const int t0 = h4.x;
  const int t1 = t0 + h4.y;
  const int t2 = t1 + h4.z;
  const int t3 = t2 + h4.w;
  const int inclH = scan_incl_addi(t3);
  const int Hb = wshr1i(inclH);              // exclusive, lane0 = 0

  {
    const int i0 = 4 * lane + 0 + Hb + t0;
    const int i1 = 4 * lane + 1 + Hb + t1;
    const int i2 = 4 * lane + 2 + Hb + t2;
    const int i3 = 4 * lane + 3 + Hb + t3;
    zfr[i0 + (i0 >> 5)] = z4.x;
    zfr[i1 + (i1 >> 5)] = z4.y;
    zfr[i2 + (i2 >> 5)] = z4.z;
    zfr[i3 + (i3 >> 5)] = z4.w;
  }

  // ---------------- fine pass (6 samples / lane, padded reads) ----------------
  const int p0 = 6 * lane;
  float zq[7];
  {
    const float2 a = *(const float2*)(zfr + p0     + (p0 >> 5));
    const float2 b = *(const float2*)(zfr + p0 + 2 + ((p0 + 2) >> 5));
    const float2 c = *(const float2*)(zfr + p0 + 4 + ((p0 + 4) >> 5));
    zq[0] = a.x; zq[1] = a.y; zq[2] = b.x; zq[3] = b.y; zq[4] = c.x; zq[5] = c.y;
    zq[6] = (lane < 63) ? zfr[p0 + 6 + ((p0 + 6) >> 5)] : 0.0f;
  }

  float dlf[6];
#pragma unroll
  for (int j = 0; j < 5; ++j) dlf[j] = zq[j + 1] - zq[j];
  dlf[5] = (lane == 63) ? FARV : (zq[6] - zq[5]);

  const float* fd = fine_density + (size_t)ray * NF + p0;
  const float2 q0 = *(const float2*)(fd);
  const float2 q1 = *(const float2*)(fd + 2);
  const float2 q2 = *(const float2*)(fd + 4);
  const float fdv[6] = {q0.x, q0.y, q1.x, q1.y, q2.x, q2.y};

  float ee[6];
#pragma unroll
  for (int j = 0; j < 6; ++j) ee[j] = __expf(-fdv[j] * dlf[j]);

  float P[6];
  P[0] = 1.0f;
#pragma unroll
  for (int j = 1; j < 6; ++j) P[j] = P[j - 1] * ee[j - 1];
  const float ftot = P[5] * ee[5];

  const float incF = scan_incl_mul(ftot);
  const float Tb2 = wshr1(incF, 1.0f);

  float wfv[6];
  float fdep = 0.0f;
#pragma unroll
  for (int j = 0; j < 6; ++j) {
    wfv[j] = Tb2 * P[j] * (1.0f - ee[j]) + 1e-10f;
    fdep += wfv[j] * zq[j];
  }

  // ---------------- feature accumulation: 6 samples/lane, register-only ------
  // features for samples 6l..6l+5 live at flat [18l .. 18l+17]; 9 x float2
  const float* fbp = fine_feature + (size_t)ray * (NF * 3) + lane * 18;
  const float2 ff0 = *(const float2*)(fbp);
  const float2 ff1 = *(const float2*)(fbp + 2);
  const float2 ff2 = *(const float2*)(fbp + 4);
  const float2 ff3 = *(const float2*)(fbp + 6);
  const float2 ff4 = *(const float2*)(fbp + 8);
  const float2 ff5 = *(const float2*)(fbp + 10);
  const float2 ff6 = *(const float2*)(fbp + 12);
  const float2 ff7 = *(const float2*)(fbp + 14);
  const float2 ff8 = *(const float2*)(fbp + 16);

  float gx = wfv[0] * ff0.x + wfv[1] * ff1.y + wfv[2] * ff3.x
           + wfv[3] * ff4.y + wfv[4] * ff6.x + wfv[5] * ff7.y;
  float gy = wfv[0] * ff0.y + wfv[1] * ff2.x + wfv[2] * ff3.y
           + wfv[3] * ff5.x + wfv[4] * ff6.y + wfv[5] * ff8.x;
  float gz = wfv[0] * ff1.x + wfv[1] * ff2.y + wfv[2] * ff4.x
           + wfv[3] * ff5.y + wfv[4] * ff7.x + wfv[5] * ff8.y;

  // ---------------- reductions (DPP, result in lane 63) + output ----------------
  fx   = scan_incl_add(fx);
  fy   = scan_incl_add(fy);
  fz   = scan_incl_add(fz);
  dep  = scan_incl_add(dep);
  gx   = scan_incl_add(gx);
  gy   = scan_incl_add(gy);
  gz   = scan_incl_add(gz);
  fdep = scan_incl_add(fdep);

  if (lane == 63) {
    float* o = out + (size_t)ray * 8;
    *(float4*)(o)     = make_float4(fx, fy, fz, dep);
    *(float4*)(o + 4) = make_float4(gx, gy, gz, fdep);
  }
}

extern "C" void kernel_launch(void* const* d_in, const int* in_sizes, int n_in,
                              void* d_out, int out_size, void* d_ws, size_t ws_size,
                              hipStream_t stream) {
  const float* z_vals       = (const float*)d_in[0];
  const float* density      = (const float*)d_in[1];
  const float* feature      = (const float*)d_in[2];
  const float* fine_density = (const float*)d_in[3];
  const float* fine_feature = (const float*)d_in[4];
  const float* u_rand       = (const float*)d_in[5];
  float* out = (float*)d_out;

  const int B = in_sizes[0] / NC;       // 65536
  dim3 grid(B / RPB), block(RPB * 64);
  hipLaunchKernelGGL(vr_kernel, grid, block, 0, stream,
                     z_vals, density, feature, fine_density, fine_feature,
                     u_rand, out);
}

// Round 10
// 128.514 us; speedup vs baseline: 1.9005x; 1.0027x over previous
//
#include <hip/hip_runtime.h>
#include <cstdint>

#define FARV 1e10f

constexpr int NC  = 256;   // coarse samples per ray
constexpr int NS  = 128;   // importance samples per ray
constexpr int NF  = 384;   // fine samples per ray
constexpr int RPB = 4;     // rays (waves) per block
constexpr int ZFP = 400;   // padded zf row: phys = i + (i>>5), max 394

// ---------------- DPP helpers (gfx9 encodings, valid on gfx950) ----------------
template<int CTRL, int RM, int BM>
__device__ __forceinline__ float dppf(float old, float x) {
  return __int_as_float(__builtin_amdgcn_update_dpp(
      __float_as_int(old), __float_as_int(x), CTRL, RM, BM, false));
}
template<int CTRL, int RM, int BM>
__device__ __forceinline__ int dppi(int old, int x) {
  return __builtin_amdgcn_update_dpp(old, x, CTRL, RM, BM, false);
}
template<int MASK>
__device__ __forceinline__ float swzx(float x) {  // xor swizzle within 32-lane halves
  return __int_as_float(__builtin_amdgcn_ds_swizzle(
      __float_as_int(x), (MASK << 10) | 0x1f));
}
__device__ __forceinline__ float rdlane(float x, int l) {
  return __int_as_float(__builtin_amdgcn_readlane(__float_as_int(x), l));
}
__device__ __forceinline__ float frcp(float x) {   // v_rcp_f32: 1 op vs ~11 for IEEE /
  return __builtin_amdgcn_rcpf(x);
}

__device__ __forceinline__ float scan_incl_mul(float x) {
  x *= dppf<0x111, 0xf, 0xf>(1.f, x);
  x *= dppf<0x112, 0xf, 0xf>(1.f, x);
  x *= dppf<0x114, 0xf, 0xf>(1.f, x);
  x *= dppf<0x118, 0xf, 0xf>(1.f, x);
  x *= dppf<0x142, 0xa, 0xf>(1.f, x);
  x *= dppf<0x143, 0xc, 0xf>(1.f, x);
  return x;
}
__device__ __forceinline__ float scan_incl_add(float x) {
  x += dppf<0x111, 0xf, 0xf>(0.f, x);
  x += dppf<0x112, 0xf, 0xf>(0.f, x);
  x += dppf<0x114, 0xf, 0xf>(0.f, x);
  x += dppf<0x118, 0xf, 0xf>(0.f, x);
  x += dppf<0x142, 0xa, 0xf>(0.f, x);
  x += dppf<0x143, 0xc, 0xf>(0.f, x);
  return x;
}
__device__ __forceinline__ int scan_incl_addi(int x) {
  x += dppi<0x111, 0xf, 0xf>(0, x);
  x += dppi<0x112, 0xf, 0xf>(0, x);
  x += dppi<0x114, 0xf, 0xf>(0, x);
  x += dppi<0x118, 0xf, 0xf>(0, x);
  x += dppi<0x142, 0xa, 0xf>(0, x);
  x += dppi<0x143, 0xc, 0xf>(0, x);
  return x;
}
__device__ __forceinline__ float wshr1(float x, float id) { return dppf<0x138, 0xf, 0xf>(id, x); }
__device__ __forceinline__ int   wshr1i(int x)            { return dppi<0x138, 0xf, 0xf>(0, x); }
__device__ __forceinline__ float wshl1(float x)           { return dppf<0x130, 0xf, 0xf>(0.f, x); }

__device__ __forceinline__ void cmpswap_local(float& a, float& b, bool asc) {
  const float lo = fminf(a, b), hi = fmaxf(a, b);
  a = asc ? lo : hi;
  b = asc ? hi : lo;
}

// partner fetch: ALWAYS off the VALU issue pipe (ds_swizzle crossbar / bpermute)
template<int M>
__device__ __forceinline__ float xpartner(float v) {
  if constexpr (M <= 16) return swzx<M>(v);
  else                   return __shfl_xor(v, M);
}
template<int M>
__device__ __forceinline__ void merge_down(float& v0, float& v1, bool asc, int lane) {
  const bool tm = ((lane & M) == 0) == asc;
  const float p0 = xpartner<M>(v0);
  const float p1 = xpartner<M>(v1);
  v0 = tm ? fminf(v0, p0) : fmaxf(v0, p0);
  v1 = tm ? fminf(v1, p1) : fmaxf(v1, p1);
  if constexpr (M > 1) merge_down<M / 2>(v0, v1, asc, lane);
}
template<int K>
__device__ __forceinline__ void bitonic_stage(float& v0, float& v1, int lane) {
  const bool asc = (lane & (K >> 1)) == 0;
  merge_down<K / 4>(v0, v1, asc, lane);
  cmpswap_local(v0, v1, asc);
}
// sort 128 floats, 2/lane, elem e = 2*lane+slot, ascending
__device__ __forceinline__ void bitonic_sort128(float& v0, float& v1, int lane) {
  cmpswap_local(v0, v1, (lane & 1) == 0);
  bitonic_stage<4>(v0, v1, lane);
  bitonic_stage<8>(v0, v1, lane);
  bitonic_stage<16>(v0, v1, lane);
  bitonic_stage<32>(v0, v1, lane);
  bitonic_stage<64>(v0, v1, lane);
  bitonic_stage<128>(v0, v1, lane);
}

__global__ __launch_bounds__(256, 8) void vr_kernel(
    const float* __restrict__ z_vals,
    const float* __restrict__ density,
    const float* __restrict__ feature,
    const float* __restrict__ fine_density,
    const float* __restrict__ fine_feature,
    const float* __restrict__ u_rand,
    float* __restrict__ out)
{
  // All rows are WAVE-PRIVATE ([wid]) -> no __syncthreads anywhere.
  __shared__ __align__(16) float zv[RPB][NC];     // coarse z (sorted)
  __shared__ __align__(16) float cdfs[RPB][NC];   // cdf[0..255], float4-written
  __shared__ __align__(16) float cdfg[RPB][64];   // group heads cdf[4g]
  __shared__ __align__(16) int   Hh[RPB][NC];     // histogram of insertion idx
  __shared__ __align__(16) float zf[RPB][ZFP];    // merged z (padded)

  const int wid  = threadIdx.x >> 6;
  const int lane = threadIdx.x & 63;
  const int ray  = blockIdx.x * RPB + wid;

  float* const zfr = &zf[wid][0];

  // zero histogram
  *(int4*)(&Hh[wid][lane * 4]) = make_int4(0, 0, 0, 0);

  // load u early (latency hides under coarse pass)
  const float2 uu = *(const float2*)(u_rand + (size_t)ray * NS + lane * 2);

  // ---------------- coarse pass (4 samples / lane) ----------------
  const float4 z4 = *(const float4*)(z_vals  + (size_t)ray * NC + lane * 4);
  const float4 d4 = *(const float4*)(density + (size_t)ray * NC + lane * 4);
  const float4 fA = *(const float4*)(feature + (size_t)ray * NC * 3 + lane * 12);
  const float4 fB = *(const float4*)(feature + (size_t)ray * NC * 3 + lane * 12 + 4);
  const float4 fC = *(const float4*)(feature + (size_t)ray * NC * 3 + lane * 12 + 8);

  *(float4*)(&zv[wid][lane * 4]) = z4;

  const float znext = wshl1(z4.x);           // lane l gets lane l+1's z4.x
  const float dl0 = z4.y - z4.x;
  const float dl1 = z4.z - z4.y;
  const float dl2 = z4.w - z4.z;
  const float dl3 = (lane == 63) ? FARV : (znext - z4.w);

  const float e0 = __expf(-d4.x * dl0);
  const float e1 = __expf(-d4.y * dl1);
  const float e2 = __expf(-d4.z * dl2);
  const float e3 = __expf(-d4.w * dl3);

  const float p1 = e0, p2 = e0 * e1, p3 = p2 * e2, ptot = p3 * e3;
  const float incl = scan_incl_mul(ptot);
  const float Tb = wshr1(incl, 1.0f);        // exclusive product, lane0 = 1

  const float w0 = Tb *      (1.0f - e0) + 1e-10f;
  const float w1 = Tb * p1 * (1.0f - e1) + 1e-10f;
  const float w2 = Tb * p2 * (1.0f - e2) + 1e-10f;
  const float w3 = Tb * p3 * (1.0f - e3) + 1e-10f;

  // feature layout per lane: fA={f0.xyz,f1.x} fB={f1.yz,f2.xy} fC={f2.z,f3.xyz}
  float fx = w0 * fA.x + w1 * fA.w + w2 * fB.z + w3 * fC.y;
  float fy = w0 * fA.y + w1 * fB.x + w2 * fB.w + w3 * fC.z;
  float fz = w0 * fA.z + w1 * fB.y + w2 * fC.x + w3 * fC.w;
  float dep = w0 * z4.x + w1 * z4.y + w2 * z4.z + w3 * z4.w;

  // ---------------- CDF over w[1:255] ----------------
  const float wn0 = wshl1(w0);               // next lane's w0 (lane63 guarded)
  const bool l63 = (lane == 63);
  const float m0 = w1 + 1e-5f;
  const float m1 = w2 + 1e-5f;
  const float m2 = l63 ? 0.0f : (w3 + 1e-5f);
  const float m3 = l63 ? 0.0f : (wn0 + 1e-5f);
  const float c1 = m0 + m1;
  const float c2 = c1 + m2;
  const float c3 = c2 + m3;
  const float inclS = scan_incl_add(c3);
  const float Sb = wshr1(inclS, 0.0f);       // exclusive sum = cdf[4*lane] (unnorm)
  const float total = rdlane(inclS, 63);
  const float inv = frcp(total);             // v_rcp, ~1ulp (threshold 6.6e-2)
  const float SbI = Sb * inv;                // = cdfg[lane], lives in registers

  *(float4*)(&cdfs[wid][4 * lane]) =
      make_float4(SbI, (Sb + m0) * inv, (Sb + c1) * inv, (Sb + c2) * inv);
  cdfg[wid][lane] = SbI;

  // 8 super-heads (groups 8k) broadcast via readlane -- register-only level A
  const float h1 = rdlane(SbI,  8);
  const float h2 = rdlane(SbI, 16);
  const float h3 = rdlane(SbI, 24);
  const float h4s = rdlane(SbI, 32);
  const float h5 = rdlane(SbI, 40);
  const float h6 = rdlane(SbI, 48);
  const float h7 = rdlane(SbI, 56);

  // ---------------- sort the u's (rank of s == rank of u; s monotone in u) ----
  float v0 = uu.x, v1 = uu.y;
  bitonic_sort128(v0, v1, lane);             // sorted elems 2*lane, 2*lane+1

  // ---------------- importance sampling on sorted u's (2 / lane) ----------------
#pragma unroll
  for (int t = 0; t < 2; ++t) {
    const float u = t ? v1 : v0;
    // level A (registers): block k = last k with head(8k) <= u
    const int k = ((u >= h1) ? 1 : 0) + ((u >= h2) ? 1 : 0) + ((u >= h3) ? 1 : 0)
                + ((u >= h4s) ? 1 : 0) + ((u >= h5) ? 1 : 0) + ((u >= h6) ? 1 : 0)
                + ((u >= h7) ? 1 : 0);
    // level B (one LDS round, two independent float4 reads): g within block
    const float4 cA = *(const float4*)(&cdfg[wid][8 * k]);
    const float4 cB = *(const float4*)(&cdfg[wid][8 * k + 4]);
    const int g = 8 * k
                + ((u >= cA.y) ? 1 : 0) + ((u >= cA.z) ? 1 : 0) + ((u >= cA.w) ? 1 : 0)
                + ((u >= cB.x) ? 1 : 0) + ((u >= cB.y) ? 1 : 0) + ((u >= cB.z) ? 1 : 0)
                + ((u >= cB.w) ? 1 : 0);
    // level C (one LDS round, two independent float4 reads)
    const int g4 = 4 * g;
    const float4 f4 = *(const float4*)(&cdfs[wid][g4]);
    const float4 f4b = *(const float4*)(&cdfs[wid][(g4 + 4 <= 252) ? g4 + 4 : 252]);
    const float nxt = f4b.x;                 // cdfs[4g+4] for g<63; guarded for g=63
    const int ind = g4 + 1 + ((u >= f4.y) ? 1 : 0) + ((u >= f4.z) ? 1 : 0)
                           + ((u >= f4.w) ? 1 : 0);          // upper_bound
    const int below = (ind - 1 < 254) ? ind - 1 : 254;
    const int r = ind - g4;                                  // 1..4
    const float cb = (r == 1) ? f4.x : (r == 2) ? f4.y : (r == 3) ? f4.z : f4.w;
    float ca = (r == 1) ? f4.y : (r == 2) ? f4.z : (r == 3) ? f4.w : nxt;
    if (ind > 254) ca = f4.z;                // matches validated round-6 guard
    const float zb0 = zv[wid][below];
    const float zb1 = zv[wid][below + 1];
    const float zb2 = zv[wid][(below + 2 < 256) ? below + 2 : 255];
    const float bb = 0.5f * (zb0 + zb1);
    const float ba = 0.5f * (zb1 + zb2);
    float den = ca - cb;
    den = (den < 1e-5f) ? 1.0f : den;
    const float tt = (u - cb) * frcp(den);   // v_rcp instead of IEEE divide
    const float s = bb + tt * (ba - bb);
    // insertion position among coarse z: s in [zv[below], zv[below+2]]
    int u_ = below + 1 + ((s >= zb1) ? 1 : 0) + ((s >= zb2) ? 1 : 0);
    const int up = (u_ > 255) ? 255 : u_;
    atomicAdd(&Hh[wid][up], 1);
    // among-samples rank == sorted index; scatter into padded zf
    const int si = up + 2 * lane + t;
    zfr[si + (si >> 5)] = s;
  }

  // z ranks: i + inclusive-prefix of histogram at i
  const int4 h4 = *(const int4*)(&Hh[wid][4 * lane]);
  const int t0 = h4.x;
  const int t1 = t0 + h4.y;
  const int t2 = t1 + h4.z;
  const int t3 = t2 + h4.w;
  const int inclH = scan_incl_addi(t3);
  const int Hb = wshr1i(inclH);              // exclusive, lane0 = 0

  {
    const int i0 = 4 * lane + 0 + Hb + t0;
    const int i1 = 4 * lane + 1 + Hb + t1;
    const int i2 = 4 * lane + 2 + Hb + t2;
    const int i3 = 4 * lane + 3 + Hb + t3;
    zfr[i0 + (i0 >> 5)] = z4.x;
    zfr[i1 + (i1 >> 5)] = z4.y;
    zfr[i2 + (i2 >> 5)] = z4.z;
    zfr[i3 + (i3 >> 5)] = z4.w;
  }

  // ---------------- fine pass (6 samples / lane, padded reads) ----------------
  const int p0 = 6 * lane;
  float zq[7];
  {
    const float2 a = *(const float2*)(zfr + p0     + (p0 >> 5));
    const float2 b = *(const float2*)(zfr + p0 + 2 + ((p0 + 2) >> 5));
    const float2 c = *(const float2*)(zfr + p0 + 4 + ((p0 + 4) >> 5));
    zq[0] = a.x; zq[1] = a.y; zq[2] = b.x; zq[3] = b.y; zq[4] = c.x; zq[5] = c.y;
    zq[6] = (lane < 63) ? zfr[p0 + 6 + ((p0 + 6) >> 5)] : 0.0f;
  }

  float dlf[6];
#pragma unroll
  for (int j = 0; j < 5; ++j) dlf[j] = zq[j + 1] - zq[j];
  dlf[5] = (lane == 63) ? FARV : (zq[6] - zq[5]);

  const float* fd = fine_density + (size_t)ray * NF + p0;
  const float2 q0 = *(const float2*)(fd);
  const float2 q1 = *(const float2*)(fd + 2);
  const float2 q2 = *(const float2*)(fd + 4);
  const float fdv[6] = {q0.x, q0.y, q1.x, q1.y, q2.x, q2.y};

  float ee[6];
#pragma unroll
  for (int j = 0; j < 6; ++j) ee[j] = __expf(-fdv[j] * dlf[j]);

  float P[6];
  P[0] = 1.0f;
#pragma unroll
  for (int j = 1; j < 6; ++j) P[j] = P[j - 1] * ee[j - 1];
  const float ftot = P[5] * ee[5];

  const float incF = scan_incl_mul(ftot);
  const float Tb2 = wshr1(incF, 1.0f);

  float wfv[6];
  float fdep = 0.0f;
#pragma unroll
  for (int j = 0; j < 6; ++j) {
    wfv[j] = Tb2 * P[j] * (1.0f - ee[j]) + 1e-10f;
    fdep += wfv[j] * zq[j];
  }

  // ---------------- feature accumulation: 6 samples/lane, register-only ------
  // features for samples 6l..6l+5 live at flat [18l .. 18l+17]; 9 x float2
  const float* fbp = fine_feature + (size_t)ray * (NF * 3) + lane * 18;
  const float2 ff0 = *(const float2*)(fbp);
  const float2 ff1 = *(const float2*)(fbp + 2);
  const float2 ff2 = *(const float2*)(fbp + 4);
  const float2 ff3 = *(const float2*)(fbp + 6);
  const float2 ff4 = *(const float2*)(fbp + 8);
  const float2 ff5 = *(const float2*)(fbp + 10);
  const float2 ff6 = *(const float2*)(fbp + 12);
  const float2 ff7 = *(const float2*)(fbp + 14);
  const float2 ff8 = *(const float2*)(fbp + 16);

  float gx = wfv[0] * ff0.x + wfv[1] * ff1.y + wfv[2] * ff3.x
           + wfv[3] * ff4.y + wfv[4] * ff6.x + wfv[5] * ff7.y;
  float gy = wfv[0] * ff0.y + wfv[1] * ff2.x + wfv[2] * ff3.y
           + wfv[3] * ff5.x + wfv[4] * ff6.y + wfv[5] * ff8.x;
  float gz = wfv[0] * ff1.x + wfv[1] * ff2.y + wfv[2] * ff4.x
           + wfv[3] * ff5.y + wfv[4] * ff7.x + wfv[5] * ff8.y;

  // ---------------- reductions (DPP, result in lane 63) + output ----------------
  fx   = scan_incl_add(fx);
  fy   = scan_incl_add(fy);
  fz   = scan_incl_add(fz);
  dep  = scan_incl_add(dep);
  gx   = scan_incl_add(gx);
  gy   = scan_incl_add(gy);
  gz   = scan_incl_add(gz);
  fdep = scan_incl_add(fdep);

  if (lane == 63) {
    float* o = out + (size_t)ray * 8;
    *(float4*)(o)     = make_float4(fx, fy, fz, dep);
    *(float4*)(o + 4) = make_float4(gx, gy, gz, fdep);
  }
}

extern "C" void kernel_launch(void* const* d_in, const int* in_sizes, int n_in,
                              void* d_out, int out_size, void* d_ws, size_t ws_size,
                              hipStream_t stream) {
  const float* z_vals       = (const float*)d_in[0];
  const float* density      = (const float*)d_in[1];
  const float* feature      = (const float*)d_in[2];
  const float* fine_density = (const float*)d_in[3];
  const float* fine_feature = (const float*)d_in[4];
  const float* u_rand       = (const float*)d_in[5];
  float* out = (float*)d_out;

  const int B = in_sizes[0] / NC;       // 65536
  dim3 grid(B / RPB), block(RPB * 64);
  hipLaunchKernelGGL(vr_kernel, grid, block, 0, stream,
                     z_vals, density, feature, fine_density, fine_feature,
                     u_rand, out);
}